// Round 7
// baseline (348.293 us; speedup 1.0000x reference)
//
#include <hip/hip_runtime.h>
#include <cmath>

typedef _Float16 f16;
typedef _Float16 f16x8 __attribute__((ext_vector_type(8)));
typedef float    f32x4 __attribute__((ext_vector_type(4)));
typedef unsigned short u16;
typedef unsigned int   u32;
typedef unsigned long long u64;
typedef u16 us8 __attribute__((ext_vector_type(8)));
typedef u16 us4 __attribute__((ext_vector_type(4)));

#define MFMA16(a, b, c) __builtin_amdgcn_mfma_f32_16x16x32_f16((a), (b), (c), 0, 0, 0)

__device__ __forceinline__ void gload_lds16(const void* g, void* l) {
    __builtin_amdgcn_global_load_lds((const __attribute__((address_space(1))) void*)g,
                                     (__attribute__((address_space(3))) void*)l, 16, 0, 0);
}

// ---------------- elementwise f32 -> f16 cast (8 elems / thread) ----------------
__global__ void castk(const float* __restrict__ src, f16* __restrict__ dst, int n8) {
    int i = blockIdx.x * 256 + threadIdx.x;
    if (i >= n8) return;
    const float4* s = (const float4*)src + (size_t)i * 2;
    float4 a = s[0], b = s[1];
    union { f16 h[8]; us8 v; } o;
    o.h[0] = (f16)a.x; o.h[1] = (f16)a.y; o.h[2] = (f16)a.z; o.h[3] = (f16)a.w;
    o.h[4] = (f16)b.x; o.h[5] = (f16)b.y; o.h[6] = (f16)b.z; o.h[7] = (f16)b.w;
    *(us8*)&dst[(size_t)i * 8] = o.v;
}

// ---------------- per-batch transpose+cast: O[b][s][h] f32 -> OT[b][h][s] f16 ----
__global__ void transpose_cast(const float* __restrict__ O, f16* __restrict__ OT) {
    __shared__ f16 tbuf[64][68];
    int bid = blockIdx.x;
    int b = bid >> 8, t = bid & 255;
    int s0 = (t & 31) * 64, h0 = (t >> 5) * 64;
    const float* Ob = O + (size_t)b * 2048 * 512;
    f16* OTb = OT + (size_t)b * 512 * 2048;
    int tid = threadIdx.x;
    int rr = tid >> 4, cc = (tid & 15) * 4;
#pragma unroll
    for (int i = 0; i < 4; ++i) {
        int r = rr + 16 * i;
        float4 v = *(const float4*)&Ob[(size_t)(s0 + r) * 512 + h0 + cc];
        tbuf[r][cc + 0] = (f16)v.x; tbuf[r][cc + 1] = (f16)v.y;
        tbuf[r][cc + 2] = (f16)v.z; tbuf[r][cc + 3] = (f16)v.w;
    }
    __syncthreads();
#pragma unroll
    for (int i = 0; i < 4; ++i) {
        int hr = rr + 16 * i;
        union { f16 h[4]; us4 v; } pk;
        pk.h[0] = tbuf[cc + 0][hr]; pk.h[1] = tbuf[cc + 1][hr];
        pk.h[2] = tbuf[cc + 2][hr]; pk.h[3] = tbuf[cc + 3][hr];
        *(us4*)&OTb[(size_t)(h0 + hr) * 2048 + s0 + cc] = pk.v;
    }
}

// ---------------- GEMM1: Qf16 = tanh(Of16 * Wf16^T + bias) ----------------------
__global__ __launch_bounds__(256) void gemm1(const f16* __restrict__ A,
                                             const f16* __restrict__ W,
                                             const float* __restrict__ bias,
                                             f16* __restrict__ Qo) {
    __shared__ f16 lA[128 * 32];
    __shared__ f16 lB[128 * 32];
    const int tid = threadIdx.x;
    const int lane = tid & 63, w = tid >> 6;
    const int wm = w >> 1, wn = w & 1;
    const int bm = blockIdx.x >> 2, bn = blockIdx.x & 3;
    const int r0 = bm * 128, c0 = bn * 128;
    const int l15 = lane & 15, g = lane >> 4;
    f32x4 acc[4][4] = {};
    for (int kt = 0; kt < 16; ++kt) {
        int k0 = kt * 32;
        __syncthreads();
#pragma unroll
        for (int i = 0; i < 2; ++i) {
            int slot = i * 256 + tid;
            int row = slot >> 2, oct = slot & 3;
            int soct = oct ^ (row & 3);
            *(us8*)&lA[slot * 8] = *(const us8*)&A[(size_t)(r0 + row) * 512 + k0 + soct * 8];
            *(us8*)&lB[slot * 8] = *(const us8*)&W[(size_t)(c0 + row) * 512 + k0 + soct * 8];
        }
        __syncthreads();
        f16x8 af[4], bf[4];
#pragma unroll
        for (int mf = 0; mf < 4; ++mf) {
            int row = 64 * wm + 16 * mf + l15;
            int oct = g ^ (row & 3);
            af[mf] = *(const f16x8*)&lA[(row * 4 + oct) * 8];
        }
#pragma unroll
        for (int nf = 0; nf < 4; ++nf) {
            int row = 64 * wn + 16 * nf + l15;
            int oct = g ^ (row & 3);
            bf[nf] = *(const f16x8*)&lB[(row * 4 + oct) * 8];
        }
#pragma unroll
        for (int mf = 0; mf < 4; ++mf)
#pragma unroll
            for (int nf = 0; nf < 4; ++nf)
                acc[mf][nf] = MFMA16(af[mf], bf[nf], acc[mf][nf]);
    }
    float bv[4];
#pragma unroll
    for (int nf = 0; nf < 4; ++nf) bv[nf] = bias[c0 + 64 * wn + 16 * nf + l15];
#pragma unroll
    for (int mf = 0; mf < 4; ++mf) {
#pragma unroll
        for (int nf = 0; nf < 4; ++nf) {
#pragma unroll
            for (int r = 0; r < 4; ++r) {
                float y = tanhf(acc[mf][nf][r] + bv[nf]);
                int row = r0 + 64 * wm + 16 * mf + 4 * g + r;
                int col = c0 + 64 * wn + 16 * nf + l15;
                Qo[(size_t)row * 512 + col] = (f16)y;
            }
        }
    }
}

// ---------------- fused attention: producer/consumer waves ----------------------
// 256 blocks (b = blk&7 XCD-pinned, qt = blk>>3), 512 threads = 8 waves.
// Waves 0-3 (S): Q in regs; compute S^T = K*Q^T + online softmax; write P(f16)+corr.
// Waves 4-7 (PV): acc[8hf][4qi]; PV of tile i-1 overlaps QK^T of tile i.
// K staged 1 tile ahead; V staged this-iter-used-next; counted vmcnt(8) steady.
// Per-wave regs: S ~130, PV ~200 (128 acc in AGPR) -> fits 256 @ 2 waves/SIMD.
__global__ __launch_bounds__(512, 1) void attn(const f16* __restrict__ Qf,
                                               const f16* __restrict__ Of,
                                               const f16* __restrict__ OfT,
                                               float* __restrict__ Out) {
    extern __shared__ __align__(16) char smem[];
    // layout: K0 @0 (32K) | K1 @32K | V0 @64K | V1 @96K | P0 @128K (4K) | P1 | corr0/1 | linv
    f16* lK0 = (f16*)(smem);
    f16* lK1 = (f16*)(smem + 32768);
    f16* lV0 = (f16*)(smem + 65536);
    f16* lV1 = (f16*)(smem + 98304);
    f16* lP0 = (f16*)(smem + 131072);
    f16* lP1 = (f16*)(smem + 135168);
    float* lc0 = (float*)(smem + 139264);
    float* lc1 = (float*)(smem + 139520);
    float* linv = (float*)(smem + 139776);

    const int tid = threadIdx.x;
    const int lane = tid & 63, w = tid >> 6;
    const int l15 = lane & 15, g = lane >> 4;
    const int b = blockIdx.x & 7, qt = blockIdx.x >> 3;
    const int q0 = qt * 64;
    const bool isS = (w < 4);
    const int sw = w & 3;
    const f16* Ob  = Of  + (size_t)b * 2048 * 512;
    const f16* OTb = OfT + (size_t)b * 512 * 2048;

    // per-lane granule-XOR key (same formula for P rows (q) and V rows (h))
    const int kx = (l15 & 3) ^ ((l15 >> 2) & 3);
    const int go = g ^ kx;

    // K tile [32t][512k] rows 1KB, octet swizzle oct^(t&7) (R2-proven)
    auto STAGE_K = [&](f16* dst, int t0) {
#pragma unroll
        for (int i = 0; i < 4; ++i) {
            int slot = i * 512 + tid;
            int t = slot >> 6, oct = slot & 63;
            gload_lds16(&Ob[(size_t)(t0 + t) * 512 + 8 * (oct ^ (t & 7))], &dst[slot * 8]);
        }
    };
    // V^T tile [512h][32t] rows 64B, 16B-granule swizzle gr ^ (h&3) ^ ((h>>2)&3)
    auto STAGE_V = [&](f16* dst, int t0) {
#pragma unroll
        for (int i = 0; i < 4; ++i) {
            int slot = i * 512 + tid;
            int h = slot >> 2, gr = slot & 3;
            int key = (h & 3) ^ ((h >> 2) & 3);
            gload_lds16(&OTb[(size_t)h * 2048 + t0 + 8 * (gr ^ key)], &dst[slot * 8]);
        }
    };

    // S-wave state
    f16x8 qf[16];
    float m = -INFINITY, lsum = 0.f;
    // PV-wave state
    f32x4 acc[8][4] = {};

    if (isS) {
        const f16* qrow = Qf + ((size_t)b * 2048 + q0 + 16 * sw + l15) * 512;
#pragma unroll
        for (int ks = 0; ks < 16; ++ks) qf[ks] = *(const f16x8*)&qrow[ks * 32 + g * 8];
    }

    STAGE_K(lK0, 0);

    // -------- producer body: QK^T + softmax + P/corr write --------
    auto SSTEP = [&](const f16* lKc, f16* lPc, float* lcc) {
        f32x4 sa0 = {}, sa1 = {};
#pragma unroll
        for (int ks = 0; ks < 16; ++ks) {
            f16x8 k0 = *(const f16x8*)&lKc[((l15)      * 64 + ((4 * ks + g) ^ (l15 & 7))) * 8];
            f16x8 k1 = *(const f16x8*)&lKc[((16 + l15) * 64 + ((4 * ks + g) ^ (l15 & 7))) * 8];
            sa0 = MFMA16(k0, qf[ks], sa0);
            sa1 = MFMA16(k1, qf[ks], sa1);
        }
        float tmax = fmaxf(fmaxf(fmaxf(sa0[0], sa0[1]), fmaxf(sa0[2], sa0[3])),
                           fmaxf(fmaxf(sa1[0], sa1[1]), fmaxf(sa1[2], sa1[3])));
        tmax = fmaxf(tmax, __shfl_xor(tmax, 16));
        tmax = fmaxf(tmax, __shfl_xor(tmax, 32));
        float corr = 1.0f;
        if (__any(tmax > m + 8.0f)) {
            float mnew = fmaxf(m, tmax);
            corr = __expf(m - mnew);
            m = mnew;
            lsum *= corr;
        }
        float p0[4], p1[4], ps = 0.f;
#pragma unroll
        for (int r = 0; r < 4; ++r) { p0[r] = __expf(sa0[r] - m); ps += p0[r]; }
#pragma unroll
        for (int r = 0; r < 4; ++r) { p1[r] = __expf(sa1[r] - m); ps += p1[r]; }
        ps += __shfl_xor(ps, 16);
        ps += __shfl_xor(ps, 32);
        lsum += ps;
        if (g == 0) lcc[16 * sw + l15] = corr;
        // pack 4 f16 per mf, write 8B at row q, t0 = 16mf+4g (granule 2mf+(g>>1), sub g&1)
        const int qloc = 16 * sw + l15;
        union { f16 h[4]; u64 u; } pk0, pk1;
#pragma unroll
        for (int r = 0; r < 4; ++r) { pk0.h[r] = (f16)p0[r]; pk1.h[r] = (f16)p1[r]; }
        *(u64*)&lPc[qloc * 32 + (((g >> 1))     ^ kx) * 8 + (g & 1) * 4] = pk0.u;
        *(u64*)&lPc[qloc * 32 + (((g >> 1) + 2) ^ kx) * 8 + (g & 1) * 4] = pk1.u;
    };

    // -------- consumer body: rescale + PV over previous tile --------
    auto PVSTEP = [&](const f16* lVp, const f16* lPp, const float* lcp) {
        float c0 = lcp[l15], c1 = lcp[16 + l15], c2 = lcp[32 + l15], c3 = lcp[48 + l15];
        f16x8 pf0 = *(const f16x8*)&lPp[(l15)      * 32 + go * 8];
        f16x8 pf1 = *(const f16x8*)&lPp[(16 + l15) * 32 + go * 8];
        f16x8 pf2 = *(const f16x8*)&lPp[(32 + l15) * 32 + go * 8];
        f16x8 pf3 = *(const f16x8*)&lPp[(48 + l15) * 32 + go * 8];
#pragma unroll
        for (int hf = 0; hf < 8; ++hf) {
            acc[hf][0] *= c0; acc[hf][1] *= c1; acc[hf][2] *= c2; acc[hf][3] *= c3;
        }
#pragma unroll
        for (int hf = 0; hf < 8; ++hf) {
            int h = 128 * sw + 16 * hf + l15;
            f16x8 vf = *(const f16x8*)&lVp[h * 32 + go * 8];
            acc[hf][0] = MFMA16(vf, pf0, acc[hf][0]);
            acc[hf][1] = MFMA16(vf, pf1, acc[hf][1]);
            acc[hf][2] = MFMA16(vf, pf2, acc[hf][2]);
            acc[hf][3] = MFMA16(vf, pf3, acc[hf][3]);
        }
    };

    auto ITER = [&](int kt, f16* lKc, f16* lKn, f16* lVc, f16* lPc, float* lcc,
                    const f16* lVp, const f16* lPp, const float* lcp) {
        if (kt < 63) STAGE_K(lKn, (kt + 1) * 32);
        STAGE_V(lVc, kt * 32);
        // steady state: drain K[kt] + V[kt-1] (oldest 8), keep K[kt+1] + V[kt] in flight
        if (kt < 63) asm volatile("s_waitcnt vmcnt(8)" ::: "memory");
        else         asm volatile("s_waitcnt vmcnt(4)" ::: "memory");
        __builtin_amdgcn_s_barrier();
        if (isS) {
            SSTEP(lKc, lPc, lcc);
        } else if (kt > 0) {
            PVSTEP(lVp, lPp, lcp);
        }
        asm volatile("s_waitcnt lgkmcnt(0)" ::: "memory");
        __builtin_amdgcn_s_barrier();
    };

    for (int k2 = 0; k2 < 32; ++k2) {
        ITER(2 * k2,     lK0, lK1, lV0, lP0, lc0, lV1, lP1, lc1);
        ITER(2 * k2 + 1, lK1, lK0, lV1, lP1, lc1, lV0, lP0, lc0);
    }

    // -------- epilogue: final PV (tile 63, parity 1) + normalize + store --------
    if (isS) {
        if (g == 0) linv[16 * sw + l15] = 1.0f / lsum;
    } else {
        asm volatile("s_waitcnt vmcnt(0)" ::: "memory");  // V[63] landed
        PVSTEP(lV1, lP1, lc1);
    }
    asm volatile("s_waitcnt lgkmcnt(0)" ::: "memory");
    __builtin_amdgcn_s_barrier();
    if (!isS) {
        float v0 = linv[l15], v1 = linv[16 + l15], v2 = linv[32 + l15], v3 = linv[48 + l15];
#pragma unroll
        for (int hf = 0; hf < 8; ++hf) {
            acc[hf][0] *= v0; acc[hf][1] *= v1; acc[hf][2] *= v2; acc[hf][3] *= v3;
        }
#pragma unroll
        for (int qi = 0; qi < 4; ++qi) {
            const size_t orow = ((size_t)b * 2048 + q0 + 16 * qi + l15) * 512;
#pragma unroll
            for (int hf = 0; hf < 8; ++hf) {
                float4 o;
                o.x = acc[hf][qi][0]; o.y = acc[hf][qi][1];
                o.z = acc[hf][qi][2]; o.w = acc[hf][qi][3];
                *(float4*)&Out[orow + 128 * sw + 16 * hf + 4 * g] = o;
            }
        }
    }
}

extern "C" void kernel_launch(void* const* d_in, const int* in_sizes, int n_in,
                              void* d_out, int out_size, void* d_ws, size_t ws_size,
                              hipStream_t stream) {
    const float* O  = (const float*)d_in[0];
    const float* Ww = (const float*)d_in[1];
    const float* Wb = (const float*)d_in[2];
    float* Out = (float*)d_out;
    char* ws = (char*)d_ws;
    f16* Of16 = (f16*)ws;                           // 16 MB
    f16* OT   = (f16*)(ws + ((size_t)16 << 20));    // 16 MB
    f16* Qf   = (f16*)(ws + ((size_t)32 << 20));    // 16 MB
    f16* Wf   = (f16*)(ws + ((size_t)48 << 20));    // 512 KB

    hipFuncSetAttribute((const void*)attn, hipFuncAttributeMaxDynamicSharedMemorySize, 140032);

    castk<<<4096, 256, 0, stream>>>(O, Of16, 1048576);
    castk<<<128, 256, 0, stream>>>(Ww, Wf, 32768);
    transpose_cast<<<2048, 256, 0, stream>>>(O, OT);
    gemm1<<<512, 256, 0, stream>>>(Of16, Wf, Wb, Qf);
    attn<<<256, 512, 140032, stream>>>(Qf, Of16, OT, Out);
}

// Round 8
// 210.178 us; speedup vs baseline: 1.6571x; 1.6571x over previous
//
#include <hip/hip_runtime.h>
#include <cmath>

typedef _Float16 f16;
typedef _Float16 f16x8 __attribute__((ext_vector_type(8)));
typedef float    f32x4 __attribute__((ext_vector_type(4)));
typedef unsigned short u16;
typedef unsigned int   u32;
typedef unsigned long long u64;
typedef u16 us8 __attribute__((ext_vector_type(8)));
typedef u16 us4 __attribute__((ext_vector_type(4)));

#define MFMA16(a, b, c) __builtin_amdgcn_mfma_f32_16x16x32_f16((a), (b), (c), 0, 0, 0)

__device__ __forceinline__ void gload_lds16(const void* g, void* l) {
    __builtin_amdgcn_global_load_lds((const __attribute__((address_space(1))) void*)g,
                                     (__attribute__((address_space(3))) void*)l, 16, 0, 0);
}

// ---------------- elementwise f32 -> f16 cast (8 elems / thread) ----------------
__global__ void castk(const float* __restrict__ src, f16* __restrict__ dst, int n8) {
    int i = blockIdx.x * 256 + threadIdx.x;
    if (i >= n8) return;
    const float4* s = (const float4*)src + (size_t)i * 2;
    float4 a = s[0], b = s[1];
    union { f16 h[8]; us8 v; } o;
    o.h[0] = (f16)a.x; o.h[1] = (f16)a.y; o.h[2] = (f16)a.z; o.h[3] = (f16)a.w;
    o.h[4] = (f16)b.x; o.h[5] = (f16)b.y; o.h[6] = (f16)b.z; o.h[7] = (f16)b.w;
    *(us8*)&dst[(size_t)i * 8] = o.v;
}

// ---------------- per-batch transpose+cast: O[b][s][h] f32 -> OT[b][h][s] f16 ----
__global__ void transpose_cast(const float* __restrict__ O, f16* __restrict__ OT) {
    __shared__ f16 tbuf[64][68];
    int bid = blockIdx.x;
    int b = bid >> 8, t = bid & 255;
    int s0 = (t & 31) * 64, h0 = (t >> 5) * 64;
    const float* Ob = O + (size_t)b * 2048 * 512;
    f16* OTb = OT + (size_t)b * 512 * 2048;
    int tid = threadIdx.x;
    int rr = tid >> 4, cc = (tid & 15) * 4;
#pragma unroll
    for (int i = 0; i < 4; ++i) {
        int r = rr + 16 * i;
        float4 v = *(const float4*)&Ob[(size_t)(s0 + r) * 512 + h0 + cc];
        tbuf[r][cc + 0] = (f16)v.x; tbuf[r][cc + 1] = (f16)v.y;
        tbuf[r][cc + 2] = (f16)v.z; tbuf[r][cc + 3] = (f16)v.w;
    }
    __syncthreads();
#pragma unroll
    for (int i = 0; i < 4; ++i) {
        int hr = rr + 16 * i;
        union { f16 h[4]; us4 v; } pk;
        pk.h[0] = tbuf[cc + 0][hr]; pk.h[1] = tbuf[cc + 1][hr];
        pk.h[2] = tbuf[cc + 2][hr]; pk.h[3] = tbuf[cc + 3][hr];
        *(us4*)&OTb[(size_t)(h0 + hr) * 2048 + s0 + cc] = pk.v;
    }
}

// ---------------- GEMM1: Qf16 = tanh(Of16 * Wf16^T + bias) ----------------------
__global__ __launch_bounds__(256) void gemm1(const f16* __restrict__ A,
                                             const f16* __restrict__ W,
                                             const float* __restrict__ bias,
                                             f16* __restrict__ Qo) {
    __shared__ f16 lA[128 * 32];
    __shared__ f16 lB[128 * 32];
    const int tid = threadIdx.x;
    const int lane = tid & 63, w = tid >> 6;
    const int wm = w >> 1, wn = w & 1;
    const int bm = blockIdx.x >> 2, bn = blockIdx.x & 3;
    const int r0 = bm * 128, c0 = bn * 128;
    const int l15 = lane & 15, g = lane >> 4;
    f32x4 acc[4][4] = {};
    for (int kt = 0; kt < 16; ++kt) {
        int k0 = kt * 32;
        __syncthreads();
#pragma unroll
        for (int i = 0; i < 2; ++i) {
            int slot = i * 256 + tid;
            int row = slot >> 2, oct = slot & 3;
            int soct = oct ^ (row & 3);
            *(us8*)&lA[slot * 8] = *(const us8*)&A[(size_t)(r0 + row) * 512 + k0 + soct * 8];
            *(us8*)&lB[slot * 8] = *(const us8*)&W[(size_t)(c0 + row) * 512 + k0 + soct * 8];
        }
        __syncthreads();
        f16x8 af[4], bf[4];
#pragma unroll
        for (int mf = 0; mf < 4; ++mf) {
            int row = 64 * wm + 16 * mf + l15;
            int oct = g ^ (row & 3);
            af[mf] = *(const f16x8*)&lA[(row * 4 + oct) * 8];
        }
#pragma unroll
        for (int nf = 0; nf < 4; ++nf) {
            int row = 64 * wn + 16 * nf + l15;
            int oct = g ^ (row & 3);
            bf[nf] = *(const f16x8*)&lB[(row * 4 + oct) * 8];
        }
#pragma unroll
        for (int mf = 0; mf < 4; ++mf)
#pragma unroll
            for (int nf = 0; nf < 4; ++nf)
                acc[mf][nf] = MFMA16(af[mf], bf[nf], acc[mf][nf]);
    }
    float bv[4];
#pragma unroll
    for (int nf = 0; nf < 4; ++nf) bv[nf] = bias[c0 + 64 * wn + 16 * nf + l15];
#pragma unroll
    for (int mf = 0; mf < 4; ++mf) {
#pragma unroll
        for (int nf = 0; nf < 4; ++nf) {
#pragma unroll
            for (int r = 0; r < 4; ++r) {
                float y = tanhf(acc[mf][nf][r] + bv[nf]);
                int row = r0 + 64 * wm + 16 * mf + 4 * g + r;
                int col = c0 + 64 * wn + 16 * nf + l15;
                Qo[(size_t)row * 512 + col] = (f16)y;
            }
        }
    }
}

// ---------------- fused attention -----------------------------------------------
// 512 blocks (b = blk&7 XCD-pinned, qt = blk>>3 in 0..63, q0 = 32*qt), 256 threads.
// 4 waves: qh = w&1 (16 q-cols), hh = w>>1 (256-h half). QK^T+softmax duplicated
// across the hh pair (identical deterministic math); PV split by h. 64KB LDS
// single-buffered {K 32KB, V^T 32KB} -> 2 blocks/CU; inter-block TLP hides
// staging latency. Per-wave regs ~190 (qf 64 + acc 64 + temps) -> no spill.
__global__ __launch_bounds__(256, 2) void attn(const f16* __restrict__ Qf,
                                               const f16* __restrict__ Of,
                                               const f16* __restrict__ OfT,
                                               float* __restrict__ Out) {
    __shared__ __align__(16) char smem[65536];
    f16* lK = (f16*)smem;            // [32 t][64 oct ^ (t&7)] 16B-octets
    f16* lV = (f16*)(smem + 32768);  // [512 h][4 gr ^ (h&3)^((h>>2)&3)] 16B-granules
    const int tid = threadIdx.x;
    const int lane = tid & 63, w = tid >> 6;
    const int l15 = lane & 15, g = lane >> 4;
    const int qh = w & 1, hh = w >> 1;
    const int b = blockIdx.x & 7, qt = blockIdx.x >> 3;
    const int q0 = qt * 32;
    const f16* Ob  = Of  + (size_t)b * 2048 * 512;
    const f16* OTb = OfT + (size_t)b * 512 * 2048;

    // Q B-fragments: q = q0 + 16*qh + l15, k = 32ks + 8g + j
    f16x8 qf[16];
    const f16* qrow = Qf + ((size_t)b * 2048 + q0 + 16 * qh + l15) * 512;
#pragma unroll
    for (int ks = 0; ks < 16; ++ks) qf[ks] = *(const f16x8*)&qrow[ks * 32 + g * 8];

    float m = -INFINITY, lsum = 0.f;
    f32x4 acc[16] = {};

    const int addrA = 4 * (32 * (g & 1) + l15);
    const int addrB = addrA + 64;
    const int kx = (l15 & 3) ^ ((l15 >> 2) & 3);  // V granule swizzle key (h = l15 mod 16)
    const int go = g ^ kx;

    for (int kt = 0; kt < 64; ++kt) {
        const int t0 = kt * 32;
        // ---- stage K (8 gloads/thread), then V (8 gloads/thread) ----
#pragma unroll
        for (int i = 0; i < 8; ++i) {
            int slot = i * 256 + tid;
            int t = slot >> 6, oct = slot & 63;
            gload_lds16(&Ob[(size_t)(t0 + t) * 512 + 8 * (oct ^ (t & 7))], &lK[slot * 8]);
        }
#pragma unroll
        for (int i = 0; i < 8; ++i) {
            int slot = i * 256 + tid;
            int h = slot >> 2, gr = slot & 3;
            int key = (h & 3) ^ ((h >> 2) & 3);
            gload_lds16(&OTb[(size_t)h * 2048 + t0 + 8 * (gr ^ key)], &lV[slot * 8]);
        }
        asm volatile("s_waitcnt vmcnt(8)" ::: "memory");  // my K landed
        __builtin_amdgcn_s_barrier();                     // => all K landed

        // ---- QK^T: S^T[32 t][16 q] ----
        f32x4 sa[2] = {};
#pragma unroll
        for (int ks = 0; ks < 16; ++ks) {
#pragma unroll
            for (int mf = 0; mf < 2; ++mf) {
                int t = 16 * mf + l15;
                int oct = (4 * ks + g) ^ (t & 7);
                f16x8 kf = *(const f16x8*)&lK[(t * 64 + oct) * 8];
                sa[mf] = MFMA16(kf, qf[ks], sa[mf]);
            }
        }

        // ---- online softmax (defer-max THR=8) ----
        float tmax = -INFINITY;
#pragma unroll
        for (int mf = 0; mf < 2; ++mf)
#pragma unroll
            for (int r = 0; r < 4; ++r) tmax = fmaxf(tmax, sa[mf][r]);
        tmax = fmaxf(tmax, __shfl_xor(tmax, 16));
        tmax = fmaxf(tmax, __shfl_xor(tmax, 32));
        if (__any(tmax > m + 8.0f)) {
            float mnew = fmaxf(m, tmax);
            float corr = __expf(m - mnew);
            m = mnew;
            lsum *= corr;
#pragma unroll
            for (int hf = 0; hf < 16; ++hf) acc[hf] *= corr;
        }
        float p[2][4];
        float ps = 0.f;
#pragma unroll
        for (int mf = 0; mf < 2; ++mf)
#pragma unroll
            for (int r = 0; r < 4; ++r) { p[mf][r] = __expf(sa[mf][r] - m); ps += p[mf][r]; }
        ps += __shfl_xor(ps, 16);
        ps += __shfl_xor(ps, 32);
        lsum += ps;

        // ---- pack P to f16, repack to B-frag via bpermute (R2-verified) ----
        u32 Wd[2][2];
#pragma unroll
        for (int mf = 0; mf < 2; ++mf)
#pragma unroll
            for (int c = 0; c < 2; ++c) {
                union { f16 h[2]; u32 u; } x;
                x.h[0] = (f16)p[mf][2 * c]; x.h[1] = (f16)p[mf][2 * c + 1];
                Wd[mf][c] = x.u;
            }
        u32 word[4];
#pragma unroll
        for (int pp = 0; pp < 4; ++pp) {
            int adr = (pp >> 1) ? addrB : addrA;
            int w0 = __builtin_amdgcn_ds_bpermute(adr, (int)Wd[0][pp & 1]);
            int w1 = __builtin_amdgcn_ds_bpermute(adr, (int)Wd[1][pp & 1]);
            word[pp] = (lane >= 32) ? (u32)w1 : (u32)w0;
        }
        union { u32 u[4]; f16x8 v; } pkk;
        pkk.u[0] = word[0]; pkk.u[1] = word[1]; pkk.u[2] = word[2]; pkk.u[3] = word[3];
        f16x8 pfrag = pkk.v;

        asm volatile("s_waitcnt vmcnt(0)" ::: "memory");  // my V landed
        __builtin_amdgcn_s_barrier();                     // => all V landed

        // ---- PV over this wave's h-half: D[h][q] += V^T[h][t] * P[q][t] ----
#pragma unroll
        for (int hf = 0; hf < 16; ++hf) {
            int h = 256 * hh + 16 * hf + l15;
            f16x8 vf = *(const f16x8*)&lV[(h * 4 + go) * 8];
            acc[hf] = MFMA16(vf, pfrag, acc[hf]);
        }

        asm volatile("s_waitcnt lgkmcnt(0)" ::: "memory");
        __builtin_amdgcn_s_barrier();   // buffer reusable
    }

    // ---- epilogue: normalize + direct float4 stores ----
    float inv = 1.0f / lsum;
    const size_t orow = ((size_t)b * 2048 + q0 + 16 * qh + l15) * 512;
#pragma unroll
    for (int hf = 0; hf < 16; ++hf) {
        float4 o;
        o.x = acc[hf][0] * inv; o.y = acc[hf][1] * inv;
        o.z = acc[hf][2] * inv; o.w = acc[hf][3] * inv;
        *(float4*)&Out[orow + 256 * hh + 16 * hf + 4 * g] = o;
    }
}

extern "C" void kernel_launch(void* const* d_in, const int* in_sizes, int n_in,
                              void* d_out, int out_size, void* d_ws, size_t ws_size,
                              hipStream_t stream) {
    const float* O  = (const float*)d_in[0];
    const float* Ww = (const float*)d_in[1];
    const float* Wb = (const float*)d_in[2];
    float* Out = (float*)d_out;
    char* ws = (char*)d_ws;
    f16* Of16 = (f16*)ws;                           // 16 MB
    f16* OT   = (f16*)(ws + ((size_t)16 << 20));    // 16 MB
    f16* Qf   = (f16*)(ws + ((size_t)32 << 20));    // 16 MB
    f16* Wf   = (f16*)(ws + ((size_t)48 << 20));    // 512 KB

    castk<<<4096, 256, 0, stream>>>(O, Of16, 1048576);
    castk<<<128, 256, 0, stream>>>(Ww, Wf, 32768);
    transpose_cast<<<2048, 256, 0, stream>>>(O, OT);
    gemm1<<<512, 256, 0, stream>>>(Of16, Wf, Wb, Qf);
    attn<<<512, 256, 0, stream>>>(Qf, Of16, OT, Out);
}